// Round 1
// baseline (105.909 us; speedup 1.0000x reference)
//
#include <hip/hip_runtime.h>
#include <hip/hip_bf16.h>
#include <math.h>

#define VN 50257   // vocab size
#define VD 512     // embedding dim
#define VP 128     // positives
#define VNEG 512   // negatives

// ---------------- helpers ----------------

__device__ __forceinline__ float block_reduce_sum_256(float val) {
    // wave (64-lane) reduce
    for (int off = 32; off > 0; off >>= 1)
        val += __shfl_down(val, off, 64);
    __shared__ float smem[4];
    int lane = threadIdx.x & 63;
    int wid  = threadIdx.x >> 6;
    if (lane == 0) smem[wid] = val;
    __syncthreads();
    if (wid == 0) {
        val = (lane < 4) ? smem[lane] : 0.f;
        for (int off = 2; off > 0; off >>= 1)
            val += __shfl_down(val, off, 64);
    }
    return val;  // valid in thread 0
}

// Dot of a length-VN row A (arbitrary 4B alignment: mis = start%4 elements)
// against cached vector x. float4 on the streaming array A, scalar (cached)
// loads on x. blockDim.x must be 256.
__device__ __forceinline__ float row_dot_256(const float* __restrict__ A,
                                             const float* __restrict__ x,
                                             int mis) {
    int t = threadIdx.x;
    int h = (4 - mis) & 3;               // scalar head elements
    float acc = 0.f;
    if (t < h) acc += A[t] * x[t];
    int nf4 = (VN - h) >> 2;
    const float4* A4 = (const float4*)(A + h);   // 16B aligned
    for (int i = t; i < nf4; i += 256) {
        float4 a = A4[i];
        int nb = h + 4 * i;
        acc += a.x * x[nb] + a.y * x[nb + 1] + a.z * x[nb + 2] + a.w * x[nb + 3];
    }
    int tail0 = h + (nf4 << 2);
    int tr = t - h;
    if (tr >= 0 && tail0 + tr < VN)
        acc += A[tail0 + tr] * x[tail0 + tr];
    return acc;
}

__device__ __forceinline__ float log_sigmoid(float q) {
    // -log(1+exp(-q)); exp argument always <= 0 for stability
    return (q < 0.f) ? (q - log1pf(__expf(q))) : (-log1pf(__expf(-q)));
}

// ---------------- kernels ----------------

// zero w accumulator (ws is poisoned 0xAA and replays accumulate via atomics)
__global__ void k_zero(float* __restrict__ w) {
    int i = blockIdx.x * blockDim.x + threadIdx.x;
    if (i < VN) w[i] = 0.f;
}

// ie[d] = dot(IE[d,:], center)  — one block per d
__global__ __launch_bounds__(256) void k_ie(const float* __restrict__ IE,
                                            const float* __restrict__ c,
                                            float* __restrict__ ie) {
    int d = blockIdx.x;
    // (d*VN) % 4 == d % 4  since VN % 4 == 1
    float acc = row_dot_256(IE + (size_t)d * VN, c, d & 3);
    acc = block_reduce_sum_256(acc);
    if (threadIdx.x == 0) ie[d] = acc;
}

// w[n] += sum_{d in chunk} ie[d] * IE[d,n]  — thread per n, 8 d-chunks of 64
__global__ __launch_bounds__(256) void k_w(const float* __restrict__ IE,
                                           const float* __restrict__ ie,
                                           float* __restrict__ w) {
    int n = blockIdx.x * blockDim.x + threadIdx.x;
    if (n >= VN) return;
    int d0 = blockIdx.y * 64;
    const float* p = IE + (size_t)d0 * VN + n;
    float acc0 = 0.f, acc1 = 0.f;
    #pragma unroll 16
    for (int i = 0; i < 64; i += 2) {
        acc0 += ie[d0 + i]     * p[(size_t)i * VN];
        acc1 += ie[d0 + i + 1] * p[(size_t)(i + 1) * VN];
    }
    atomicAdd(&w[n], acc0 + acc1);
}

// v[n] = dot(ie, OE[n,:])  — one 64-lane wave per row (rows are 2KB aligned)
__global__ __launch_bounds__(256) void k_v(const float* __restrict__ OE,
                                           const float* __restrict__ ie,
                                           float* __restrict__ v) {
    int lane = threadIdx.x & 63;
    int gw   = blockIdx.x * (blockDim.x >> 6) + (threadIdx.x >> 6);
    int nW   = gridDim.x * (blockDim.x >> 6);
    const float4* ie4 = (const float4*)ie;       // ws base: 16B aligned
    float4 e0 = ie4[lane];
    float4 e1 = ie4[64 + lane];
    for (int r = gw; r < VN; r += nW) {
        const float4* row4 = (const float4*)(OE + (size_t)r * VD);
        float4 a0 = row4[lane];
        float4 a1 = row4[64 + lane];
        float p = a0.x * e0.x + a0.y * e0.y + a0.z * e0.z + a0.w * e0.w
                + a1.x * e1.x + a1.y * e1.y + a1.z * e1.z + a1.w * e1.w;
        for (int off = 32; off > 0; off >>= 1)
            p += __shfl_down(p, off, 64);
        if (lane == 0) v[r] = p;
    }
}

// scores[r] = log_sigmoid(+dot(PW[r,:], w))        for r < 128
//           = log_sigmoid(-dot(NW[r-128,:], v))    for r >= 128
__global__ __launch_bounds__(256) void k_score(const float* __restrict__ PW,
                                               const float* __restrict__ NW,
                                               const float* __restrict__ w,
                                               const float* __restrict__ v,
                                               float* __restrict__ scores) {
    int r = blockIdx.x;
    const float* A;
    const float* x;
    if (r < VP) { A = PW + (size_t)r * VN;        x = w; }
    else        { A = NW + (size_t)(r - VP) * VN; x = v; }
    // row misalignment: (r*VN)%4 == r%4 ; ((r-128)*VN)%4 == r%4 as well
    float acc = row_dot_256(A, x, r & 3);
    float s = block_reduce_sum_256(acc);
    if (threadIdx.x == 0) {
        float q = (r < VP) ? s : -s;
        scores[r] = log_sigmoid(q);
    }
}

// out[0] = -(sum of 640 scores)
__global__ __launch_bounds__(256) void k_final(const float* __restrict__ scores,
                                               float* __restrict__ out) {
    float acc = 0.f;
    for (int i = threadIdx.x; i < VP + VNEG; i += 256)
        acc += scores[i];
    acc = block_reduce_sum_256(acc);
    if (threadIdx.x == 0) out[0] = -acc;
}

// ---------------- launcher ----------------

extern "C" void kernel_launch(void* const* d_in, const int* in_sizes, int n_in,
                              void* d_out, int out_size, void* d_ws, size_t ws_size,
                              hipStream_t stream) {
    const float* center = (const float*)d_in[0];  // [VN]
    const float* PW     = (const float*)d_in[1];  // [VP, VN]
    const float* NW     = (const float*)d_in[2];  // [VNEG, VN]
    const float* IE     = (const float*)d_in[3];  // [VD, VN]
    const float* OE     = (const float*)d_in[4];  // [VN, VD]
    float* out = (float*)d_out;

    // workspace layout (floats): ie[512] | scores[640] | w[VN] | v[VN]
    float* ws     = (float*)d_ws;
    float* ie     = ws;              // offset 0      (16B aligned)
    float* scores = ws + 512;
    float* w      = ws + 512 + 640;
    float* v      = ws + 512 + 640 + VN;

    dim3 blk(256);

    // 1. zero the w accumulator (atomics target; must be re-zeroed every call)
    k_zero<<<dim3((VN + 255) / 256), blk, 0, stream>>>(w);

    // 2. ie = IE @ center          (reads IE: 103 MB)
    k_ie<<<dim3(VD), blk, 0, stream>>>(IE, center, ie);

    // 3. w = IE^T @ ie             (re-reads IE: L3-resident)
    k_w<<<dim3((VN + 255) / 256, VD / 64), blk, 0, stream>>>(IE, ie, w);

    // 4. v[n] = ie . OE[n,:]       (reads OE: 103 MB)
    k_v<<<dim3(1024), blk, 0, stream>>>(OE, ie, v);

    // 5. per-row scores + log-sigmoid (reads PW 26 MB + NW 103 MB)
    k_score<<<dim3(VP + VNEG), blk, 0, stream>>>(PW, NW, w, v, scores);

    // 6. final reduction -> scalar
    k_final<<<dim3(1), blk, 0, stream>>>(scores, out);
}

// Round 2
// 96.266 us; speedup vs baseline: 1.1002x; 1.1002x over previous
//
#include <hip/hip_runtime.h>
#include <hip/hip_bf16.h>
#include <math.h>

#define VN 50257   // vocab size
#define VD 512     // embedding dim
#define VP 128     // positives
#define VNEG 512   // negatives
#define VN_PAD 50260  // VN rounded up to multiple of 4

// ---------------- shared helpers ----------------

__device__ __forceinline__ float block_reduce_sum_256(float val) {
    for (int off = 32; off > 0; off >>= 1)
        val += __shfl_down(val, off, 64);
    __shared__ float smem[4];
    int lane = threadIdx.x & 63;
    int wid  = threadIdx.x >> 6;
    if (lane == 0) smem[wid] = val;
    __syncthreads();
    if (wid == 0) {
        val = (lane < 4) ? smem[lane] : 0.f;
        for (int off = 2; off > 0; off >>= 1)
            val += __shfl_down(val, off, 64);
    }
    return val;  // valid in thread 0
}

__device__ __forceinline__ float log_sigmoid(float q) {
    return (q < 0.f) ? (q - log1pf(__expf(q))) : (-log1pf(__expf(-q)));
}

// Dot over n in [n0,n1) of a row A (misaligned by rmod=row%4 floats) against
// vector x, using a pre-shifted copy xsh (xsh[k] = x[h+k], 16B-aligned) so
// both streams are pure float4. x0 = unshifted x for head/tail scalars.
// n0 must be a multiple of 4. blockDim.x == 256.
__device__ __forceinline__ float seg_dot_shift(const float* __restrict__ Arow,
                                               const float* __restrict__ xsh,
                                               const float* __restrict__ x0,
                                               int h, int n0, int n1) {
    int t = threadIdx.x;
    float acc = 0.f;
    if (t < h && n0 + t < n1) acc += Arow[n0 + t] * x0[n0 + t];   // head
    int a0 = n0 + h;
    int nf4 = (n1 - a0) >> 2;
    const float4* A4 = (const float4*)(Arow + a0);   // 16B aligned
    const float4* X4 = (const float4*)(xsh + n0);    // 16B aligned
    for (int i = t; i < nf4; i += 256) {
        float4 a = A4[i];
        float4 b = X4[i];
        acc += a.x * b.x + a.y * b.y + a.z * b.z + a.w * b.w;
    }
    int tail0 = a0 + (nf4 << 2);
    if (t < 4) {
        int n = tail0 + t;
        if (n < n1) acc += Arow[n] * x0[n];
    }
    return acc;
}

// ================= FULL (fast) PATH =================
// ws layout (floats):
//   cs  [4][VN_PAD]  @ 0        shifted copies of center
//   wsh [4][VN_PAD]  @ 201040   shifted copies of w (wsh[0] == w)
//   vsh [4][VN_PAD]  @ 402080   shifted copies of v (vsh[0] == v)
//   ie  [512]        @ 603120
//   sacc[640]        @ 603632
#define OFF_CS   0
#define OFF_WSH  (4 * VN_PAD)
#define OFF_VSH  (8 * VN_PAD)
#define OFF_IE   (12 * VN_PAD)
#define OFF_SACC (12 * VN_PAD + 512)
#define WS_FULL_BYTES ((size_t)(12 * VN_PAD + 512 + 640) * 4)

// prep: build cs (4 shifted copies of center), zero ie + sacc
__global__ __launch_bounds__(256) void n_prep(const float* __restrict__ c,
                                              float* __restrict__ ws) {
    int i = blockIdx.x * 256 + threadIdx.x;
    if (i < 4 * VN_PAD) {
        int h = i / VN_PAD;
        int k = i - h * VN_PAD;
        ws[OFF_CS + i] = (k < VN - h) ? c[h + k] : 0.f;
    }
    if (i < 512) ws[OFF_IE + i] = 0.f;
    if (i < 640) ws[OFF_SACC + i] = 0.f;
}

// ie[d] += partial dot(IE[d,:], c) — 2 segments per row, 1024 blocks
__global__ __launch_bounds__(256) void n_ie(const float* __restrict__ IE,
                                            const float* __restrict__ c,
                                            float* __restrict__ ws) {
    int b = blockIdx.x;
    int d = b >> 1;
    int s = b & 1;
    int n0 = s * 25128;                    // multiple of 4
    int n1 = s ? VN : 25128;
    int h = (4 - (d & 3)) & 3;             // (d*VN)%4 == d%4 since VN%4==1
    const float* Arow = IE + (size_t)d * VN;
    float acc = seg_dot_shift(Arow, ws + OFF_CS + h * VN_PAD, c, h, n0, n1);
    float sum = block_reduce_sum_256(acc);
    if (threadIdx.x == 0) atomicAdd(&ws[OFF_IE + d], sum);
}

// fused: blocks [0,NWB) compute w = IE^T@ie (L3-resident IE re-read);
//        blocks [NWB,NWB+NVB) compute v[n] = ie . OE[n,:] (HBM stream).
// Both write 4 shifted copies of their outputs.
#define NWB 786   // ceil(VN/64)
#define NVB 1536

__global__ __launch_bounds__(256) void n_wv(const float* __restrict__ IE,
                                            const float* __restrict__ OE,
                                            float* __restrict__ ws) {
    const float* ie = ws + OFF_IE;
    int t = threadIdx.x;
    if (blockIdx.x < NWB) {
        // ---- w part: block handles 64 columns, 4 wave-groups split d ----
        __shared__ float ie_s[512];
        __shared__ float red[256];
        for (int j = t; j < 512; j += 256) ie_s[j] = ie[j];
        __syncthreads();
        int lane = t & 63;
        int g = t >> 6;
        int n = blockIdx.x * 64 + lane;
        float acc = 0.f;
        if (n < VN) {
            const float* p = IE + (size_t)(g * 128) * VN + n;
            int dbase = g * 128;
            #pragma unroll 4
            for (int i = 0; i < 128; ++i) {
                acc += ie_s[dbase + i] * (*p);
                p += VN;
            }
        }
        red[t] = acc;
        __syncthreads();
        if (t < 64) {
            int nn = blockIdx.x * 64 + t;
            if (nn < VN) {
                float s = red[t] + red[64 + t] + red[128 + t] + red[192 + t];
                #pragma unroll
                for (int h = 0; h < 4; ++h)
                    if (nn >= h) ws[OFF_WSH + h * VN_PAD + nn - h] = s;
            }
        }
    } else {
        // ---- v part: one wave per row, grid-stride ----
        int lane = t & 63;
        int gw = (blockIdx.x - NWB) * 4 + (t >> 6);
        const int nW = NVB * 4;
        const float4* ie4 = (const float4*)ie;
        float4 e0 = ie4[lane];
        float4 e1 = ie4[64 + lane];
        for (int r = gw; r < VN; r += nW) {
            const float4* row4 = (const float4*)(OE + (size_t)r * VD);
            float4 a0 = row4[lane];
            float4 a1 = row4[64 + lane];
            float p = a0.x * e0.x + a0.y * e0.y + a0.z * e0.z + a0.w * e0.w
                    + a1.x * e1.x + a1.y * e1.y + a1.z * e1.z + a1.w * e1.w;
            for (int off = 32; off > 0; off >>= 1)
                p += __shfl_down(p, off, 64);
            if (lane == 0) {
                #pragma unroll
                for (int h = 0; h < 4; ++h)
                    if (r >= h) ws[OFF_VSH + h * VN_PAD + r - h] = p;
            }
        }
    }
}

// scores: 4 segments per row, 2560 blocks; partials into sacc via atomics
__global__ __launch_bounds__(256) void n_score(const float* __restrict__ PW,
                                               const float* __restrict__ NW,
                                               float* __restrict__ ws) {
    int b = blockIdx.x;
    int r = b >> 2;
    int s = b & 3;
    int n0 = s * 12564;                    // multiple of 4
    int n1 = (s == 3) ? VN : n0 + 12564;
    int h = (4 - (r & 3)) & 3;             // row misalign == r%4 for both pos/neg
    const float* Arow;
    const float* xs;
    if (r < VP) { Arow = PW + (size_t)r * VN;        xs = ws + OFF_WSH; }
    else        { Arow = NW + (size_t)(r - VP) * VN; xs = ws + OFF_VSH; }
    float acc = seg_dot_shift(Arow, xs + h * VN_PAD, xs, h, n0, n1);
    float sum = block_reduce_sum_256(acc);
    if (threadIdx.x == 0) atomicAdd(&ws[OFF_SACC + r], sum);
}

__global__ __launch_bounds__(256) void n_final(const float* __restrict__ ws,
                                               float* __restrict__ out) {
    float acc = 0.f;
    for (int r = threadIdx.x; r < VP + VNEG; r += 256) {
        float s = ws[OFF_SACC + r];
        float q = (r < VP) ? s : -s;
        acc += log_sigmoid(q);
    }
    acc = block_reduce_sum_256(acc);
    if (threadIdx.x == 0) out[0] = -acc;
}

// ================= FALLBACK PATH (round-1, known-good) =================

__device__ __forceinline__ float row_dot_256(const float* __restrict__ A,
                                             const float* __restrict__ x,
                                             int mis) {
    int t = threadIdx.x;
    int h = (4 - mis) & 3;
    float acc = 0.f;
    if (t < h) acc += A[t] * x[t];
    int nf4 = (VN - h) >> 2;
    const float4* A4 = (const float4*)(A + h);
    for (int i = t; i < nf4; i += 256) {
        float4 a = A4[i];
        int nb = h + 4 * i;
        acc += a.x * x[nb] + a.y * x[nb + 1] + a.z * x[nb + 2] + a.w * x[nb + 3];
    }
    int tail0 = h + (nf4 << 2);
    int tr = t - h;
    if (tr >= 0 && tail0 + tr < VN)
        acc += A[tail0 + tr] * x[tail0 + tr];
    return acc;
}

__global__ void f_zero(float* __restrict__ w) {
    int i = blockIdx.x * blockDim.x + threadIdx.x;
    if (i < VN) w[i] = 0.f;
}

__global__ __launch_bounds__(256) void f_ie(const float* __restrict__ IE,
                                            const float* __restrict__ c,
                                            float* __restrict__ ie) {
    int d = blockIdx.x;
    float acc = row_dot_256(IE + (size_t)d * VN, c, d & 3);
    acc = block_reduce_sum_256(acc);
    if (threadIdx.x == 0) ie[d] = acc;
}

__global__ __launch_bounds__(256) void f_w(const float* __restrict__ IE,
                                           const float* __restrict__ ie,
                                           float* __restrict__ w) {
    int n = blockIdx.x * blockDim.x + threadIdx.x;
    if (n >= VN) return;
    int d0 = blockIdx.y * 64;
    const float* p = IE + (size_t)d0 * VN + n;
    float acc0 = 0.f, acc1 = 0.f;
    #pragma unroll 16
    for (int i = 0; i < 64; i += 2) {
        acc0 += ie[d0 + i]     * p[(size_t)i * VN];
        acc1 += ie[d0 + i + 1] * p[(size_t)(i + 1) * VN];
    }
    atomicAdd(&w[n], acc0 + acc1);
}

__global__ __launch_bounds__(256) void f_v(const float* __restrict__ OE,
                                           const float* __restrict__ ie,
                                           float* __restrict__ v) {
    int lane = threadIdx.x & 63;
    int gw   = blockIdx.x * (blockDim.x >> 6) + (threadIdx.x >> 6);
    int nW   = gridDim.x * (blockDim.x >> 6);
    const float4* ie4 = (const float4*)ie;
    float4 e0 = ie4[lane];
    float4 e1 = ie4[64 + lane];
    for (int r = gw; r < VN; r += nW) {
        const float4* row4 = (const float4*)(OE + (size_t)r * VD);
        float4 a0 = row4[lane];
        float4 a1 = row4[64 + lane];
        float p = a0.x * e0.x + a0.y * e0.y + a0.z * e0.z + a0.w * e0.w
                + a1.x * e1.x + a1.y * e1.y + a1.z * e1.z + a1.w * e1.w;
        for (int off = 32; off > 0; off >>= 1)
            p += __shfl_down(p, off, 64);
        if (lane == 0) v[r] = p;
    }
}

__global__ __launch_bounds__(256) void f_score(const float* __restrict__ PW,
                                               const float* __restrict__ NW,
                                               const float* __restrict__ w,
                                               const float* __restrict__ v,
                                               float* __restrict__ scores) {
    int r = blockIdx.x;
    const float* A;
    const float* x;
    if (r < VP) { A = PW + (size_t)r * VN;        x = w; }
    else        { A = NW + (size_t)(r - VP) * VN; x = v; }
    float acc = row_dot_256(A, x, r & 3);
    float s = block_reduce_sum_256(acc);
    if (threadIdx.x == 0) {
        float q = (r < VP) ? s : -s;
        scores[r] = log_sigmoid(q);
    }
}

__global__ __launch_bounds__(256) void f_final(const float* __restrict__ scores,
                                               float* __restrict__ out) {
    float acc = 0.f;
    for (int i = threadIdx.x; i < VP + VNEG; i += 256)
        acc += scores[i];
    acc = block_reduce_sum_256(acc);
    if (threadIdx.x == 0) out[0] = -acc;
}

// ---------------- launcher ----------------

extern "C" void kernel_launch(void* const* d_in, const int* in_sizes, int n_in,
                              void* d_out, int out_size, void* d_ws, size_t ws_size,
                              hipStream_t stream) {
    const float* center = (const float*)d_in[0];  // [VN]
    const float* PW     = (const float*)d_in[1];  // [VP, VN]
    const float* NW     = (const float*)d_in[2];  // [VNEG, VN]
    const float* IE     = (const float*)d_in[3];  // [VD, VN]
    const float* OE     = (const float*)d_in[4];  // [VN, VD]
    float* out = (float*)d_out;
    float* ws  = (float*)d_ws;
    dim3 blk(256);

    if (ws_size >= WS_FULL_BYTES) {
        // fast path: shifted-copy vectorized dots, fused w+v
        n_prep <<<dim3((4 * VN_PAD + 255) / 256), blk, 0, stream>>>(center, ws);
        n_ie   <<<dim3(2 * VD),                   blk, 0, stream>>>(IE, center, ws);
        n_wv   <<<dim3(NWB + NVB),                blk, 0, stream>>>(IE, OE, ws);
        n_score<<<dim3(4 * (VP + VNEG)),          blk, 0, stream>>>(PW, NW, ws);
        n_final<<<dim3(1),                        blk, 0, stream>>>(ws, out);
    } else {
        // fallback: round-1 path (ws usage ~407 KB)
        float* ie     = ws;
        float* scores = ws + 512;
        float* w      = ws + 512 + 640;
        float* v      = ws + 512 + 640 + VN;
        f_zero <<<dim3((VN + 255) / 256), blk, 0, stream>>>(w);
        f_ie   <<<dim3(VD),              blk, 0, stream>>>(IE, center, ie);
        f_w    <<<dim3((VN + 255) / 256, VD / 64), blk, 0, stream>>>(IE, ie, w);
        f_v    <<<dim3(1024),            blk, 0, stream>>>(OE, ie, v);
        f_score<<<dim3(VP + VNEG),       blk, 0, stream>>>(PW, NW, w, v, scores);
        f_final<<<dim3(1),               blk, 0, stream>>>(scores, out);
    }
}